// Round 9
// baseline (605.731 us; speedup 1.0000x reference)
//
#include <hip/hip_runtime.h>

using bf16   = __bf16;
using bf16x4 = __attribute__((ext_vector_type(4))) __bf16;
using bf16x8 = __attribute__((ext_vector_type(8))) __bf16;
using f32x4  = __attribute__((ext_vector_type(4))) float;

#define GLDS16(g, l)                                                            \
  __builtin_amdgcn_global_load_lds(                                             \
      (__attribute__((address_space(1))) void*)(g),                             \
      (__attribute__((address_space(3))) void*)(l), 16, 0, 0)

#define MFMA16(a, b, c) __builtin_amdgcn_mfma_f32_16x16x32_bf16(a, b, c, 0, 0, 0)

// XOR swizzle: row r, 8-elem slot s (0..7) -> elem offset within a [*][64] tile (attn)
__device__ __forceinline__ int SW(int r, int s) {
  return r * 64 + (((s ^ (r & 7) ^ ((r >> 3) & 7)) & 7) << 3);
}

__device__ __forceinline__ float b2f(unsigned short u) {
  return (float)__builtin_bit_cast(bf16, u);
}

// exact: x/8 is an exponent decrement in bf16 (no mantissa change here)
__device__ __forceinline__ bf16x8 scale8th(bf16x8 v) {
  bf16x8 r;
#pragma unroll
  for (int i = 0; i < 8; ++i) r[i] = (bf16)((float)v[i] * 0.125f);
  return r;
}

// ---------------------------------------------------------------- prep: one dispatch for init_pe (z=0) + 5 weight cvts (z=1..5)
// z=0: xbf = q+pe, ybf = qa+pe (bf16 residual stream), grid-stride
// z>=1: fp32 -> bf16 weight converts
__global__ __launch_bounds__(256)
void prep(const float4* __restrict__ qd, const float4* __restrict__ qa,
          ushort4* __restrict__ xbf, ushort4* __restrict__ ybf,
          const float4* __restrict__ s0, const float4* __restrict__ s1,
          const float4* __restrict__ s2, const float4* __restrict__ s3,
          const float4* __restrict__ s4,
          ushort4* __restrict__ dDD, ushort4* __restrict__ dDF,
          int n4dd, int n4df) {
  const int z = blockIdx.z;
  if (z == 0) {
    const int n4 = 8 * 1024 * 1024 / 4;  // B*S*D / 4
    for (int i = blockIdx.x * 256 + threadIdx.x; i < n4; i += gridDim.x * 256) {
      int d4 = (i & 255) * 4;          // feature index 0..1023 step 4
      int ss = (i >> 8) & 1023;        // position
      const float c = -0.0089944730195177f;  // -ln(10000)/1024
      float a0 = (float)ss * __expf((float)d4 * c);
      float a1 = (float)ss * __expf((float)(d4 + 2) * c);
      float p0 = sinf(a0), p1 = cosf(a0), p2 = sinf(a1), p3 = cosf(a1);
      float4 q4 = qd[i], y4 = qa[i];
      ushort4 xb, yb;
      xb.x = __builtin_bit_cast(unsigned short, (bf16)(q4.x + p0));
      xb.y = __builtin_bit_cast(unsigned short, (bf16)(q4.y + p1));
      xb.z = __builtin_bit_cast(unsigned short, (bf16)(q4.z + p2));
      xb.w = __builtin_bit_cast(unsigned short, (bf16)(q4.w + p3));
      yb.x = __builtin_bit_cast(unsigned short, (bf16)(y4.x + p0));
      yb.y = __builtin_bit_cast(unsigned short, (bf16)(y4.y + p1));
      yb.z = __builtin_bit_cast(unsigned short, (bf16)(y4.z + p2));
      yb.w = __builtin_bit_cast(unsigned short, (bf16)(y4.w + p3));
      xbf[i] = xb; ybf[i] = yb;
    }
  } else {
    const int w = z - 1;
    const float4* s = (w == 0) ? s0 : (w == 1) ? s1 : (w == 2) ? s2
                                    : (w == 3) ? s3 : s4;
    ushort4* dd = (w < 3) ? dDD + (size_t)w * n4dd : dDF + (size_t)(w - 3) * n4df;
    const int n4 = (w < 3) ? n4dd : n4df;
    for (int i = blockIdx.x * 256 + threadIdx.x; i < n4; i += gridDim.x * 256) {
      float4 v = s[i];
      ushort4 o;
      o.x = __builtin_bit_cast(unsigned short, (bf16)v.x);
      o.y = __builtin_bit_cast(unsigned short, (bf16)v.y);
      o.z = __builtin_bit_cast(unsigned short, (bf16)v.z);
      o.w = __builtin_bit_cast(unsigned short, (bf16)v.w);
      dd[i] = o;
    }
  }
}

// ---------------------------------------------------------------- m97-faithful GEMM (R11: 885 TF, at structure ceiling)
// C[M,N] = A[M,K]*W[N,K]^T + bias.  128x128 tile, 256 thr (4 waves, 2x2), BK=64,
// single-buffered 32 KiB LDS, 4 blocks/CU TLP. Swizzle: LDS[r][s]=G[r][s^(r&7)].
// EPI: 0 bf16, 1 bf16+relu.
// MODE: 0 plain; 1 pair (z selects operand set; z=1 writes C TRANSPOSED per
//       head: C1[bh][d=0..63][s=0..1023], for attention V).
// RES (MODE 0 only): epilogue adds the residual tile from A1 (same [row][N]
//       addressing as C) in f32 before the bf16 store — fused residual-add
//       so add_ln reads one buffer instead of two.
template <int EPI, int MODE, int RES>
__global__ __launch_bounds__(256, 4)
void gemm_s(const bf16* __restrict__ A0, const bf16* __restrict__ W0,
            const float* __restrict__ b0, void* __restrict__ C0,
            const bf16* __restrict__ A1, const bf16* __restrict__ W1,
            const float* __restrict__ b1, void* __restrict__ C1,
            const int N, const int K) {
  __shared__ bf16 L[2][128 * 64];  // [0=A,1=B], 32 KiB

  const int tid = threadIdx.x;
  const int wave = tid >> 6, lane = tid & 63;
  const int wm = wave >> 1, wn = wave & 1;   // 2 x 2 wave grid, 64x64 per wave
  const int cl = lane & 15, hk = lane >> 4;

  // XCD-aware bijective block swizzle (nwg divisible by 8 for all our grids)
  const int gx = gridDim.x;
  int flat = blockIdx.y * gx + blockIdx.x;
  flat = (flat & 7) * ((gx * gridDim.y) >> 3) + (flat >> 3);
  const int bcol = flat % gx, brow = flat / gx;
  const int z = (MODE == 0) ? 0 : blockIdx.z;

  const bf16* A = (MODE == 1 && z) ? A1 : A0;
  const bf16* W = (MODE == 1 && z) ? W1 : W0;
  const float* bias = (MODE == 1 && z) ? b1 : b0;
  void* C = (MODE == 1 && z) ? C1 : C0;

  const bf16* Ablk = A + (size_t)brow * 128 * K;
  const bf16* Wblk = W + (size_t)bcol * 128 * K;

  const int strow8 = lane >> 3;
  const int sl8 = (lane & 7) ^ (lane >> 3);

#define STAGE(kt)                                                               \
  do {                                                                          \
    _Pragma("unroll") for (int i_ = 0; i_ < 4; ++i_) {                          \
      int r0_ = i_ * 32 + wave * 8;                                             \
      GLDS16(Ablk + (size_t)(r0_ + strow8) * K + (size_t)(kt) * 64 + sl8 * 8,   \
             &L[0][r0_ * 64]);                                                  \
      GLDS16(Wblk + (size_t)(r0_ + strow8) * K + (size_t)(kt) * 64 + sl8 * 8,   \
             &L[1][r0_ * 64]);                                                  \
    }                                                                           \
  } while (0)

#define RD(reg, r_, kk_) \
  (*(const bf16x8*)&L[reg][(r_) * 64 + ((((kk_) * 4 + hk) ^ (cl & 7)) * 8)])

  f32x4 acc[4][4] = {};
  const int NT = K >> 6;

  for (int t = 0; t < NT; ++t) {
    STAGE(t);
    __syncthreads();
#pragma unroll
    for (int kk = 0; kk < 2; ++kk) {
      bf16x8 a4[4], b4[4];
#pragma unroll
      for (int m = 0; m < 4; ++m) a4[m] = RD(0, wm * 64 + m * 16 + cl, kk);
#pragma unroll
      for (int n = 0; n < 4; ++n) b4[n] = RD(1, wn * 64 + n * 16 + cl, kk);
      __builtin_amdgcn_s_setprio(1);
#pragma unroll
      for (int m = 0; m < 4; ++m)
#pragma unroll
        for (int n = 0; n < 4; ++n)
          acc[m][n] = MFMA16(a4[m], b4[n], acc[m][n]);
      __builtin_amdgcn_s_setprio(0);
    }
    __syncthreads();
  }
#undef STAGE
#undef RD

  float bv[4];
#pragma unroll
  for (int n = 0; n < 4; ++n)
    bv[n] = bias[bcol * 128 + wn * 64 + n * 16 + cl];

  const int crow0 = brow * 128 + wm * 64;
  const int ccol0 = bcol * 128 + wn * 64;
  char* esmem = (char*)(&L[0][0]) + wave * 4608;

  if (MODE == 1 && z == 1) {
    // V^T epilogue: C1[bh][d][s]
    bf16* ep = (bf16*)esmem;
    const int h_ = ccol0 >> 6;
#pragma unroll
    for (int mp = 0; mp < 2; ++mp) {
#pragma unroll
      for (int mb = 0; mb < 2; ++mb) {
        int m = mp * 2 + mb;
#pragma unroll
        for (int n = 0; n < 4; ++n) {
          bf16x4 w4;
#pragma unroll
          for (int j = 0; j < 4; ++j) w4[j] = (bf16)(acc[m][n][j] + bv[n]);
          *(bf16x4*)&ep[(n * 16 + cl) * 36 + mb * 16 + hk * 4] = w4;
        }
      }
      asm volatile("s_waitcnt lgkmcnt(0)" ::: "memory");
      __builtin_amdgcn_sched_barrier(0);
      {
        const int t0 = crow0 + mp * 32;
        const int b_ = t0 >> 10, s_ = t0 & 1023;
        bf16* dst = (bf16*)C + ((size_t)(b_ * 16 + h_) * 64 + lane) * 1024 + s_;
        const bf16* src = &ep[lane * 36];
#pragma unroll
        for (int i = 0; i < 4; ++i)
          *(bf16x8*)&dst[i * 8] = *(const bf16x8*)&src[i * 8];
      }
      asm volatile("s_waitcnt lgkmcnt(0)" ::: "memory");
      __builtin_amdgcn_sched_barrier(0);
    }
  } else {
    // prefetch residual tiles (coalesced 16B, latencies overlap)
    bf16x8 rr_[4][2];
    if (RES) {
#pragma unroll
      for (int m = 0; m < 4; ++m)
#pragma unroll
        for (int i = 0; i < 2; ++i) {
          const int row = crow0 + m * 16 + 8 * i + (lane >> 3);
          rr_[m][i] = *(const bf16x8*)(A1 + (size_t)row * N + ccol0 +
                                       (lane & 7) * 8);
        }
    }
#pragma unroll
    for (int m = 0; m < 4; ++m) {
      bf16* ep = (bf16*)esmem;
#pragma unroll
      for (int n = 0; n < 4; ++n)
#pragma unroll
        for (int j = 0; j < 4; ++j) {
          float val = acc[m][n][j] + bv[n];
          if (EPI == 1) val = fmaxf(val, 0.f);
          ep[(hk * 4 + j) * 64 + n * 16 + cl] = (bf16)val;
        }
      asm volatile("s_waitcnt lgkmcnt(0)" ::: "memory");
      __builtin_amdgcn_sched_barrier(0);
#pragma unroll
      for (int i = 0; i < 2; ++i) {
        bf16x8 vv = ((const bf16x8*)ep)[lane + i * 64];
        if (RES) {
#pragma unroll
          for (int j = 0; j < 8; ++j)
            vv[j] = (bf16)((float)vv[j] + (float)rr_[m][i][j]);
        }
        const int row = crow0 + m * 16 + 8 * i + (lane >> 3);
        *(bf16x8*)((bf16*)C + (size_t)row * N + ccol0 + (lane & 7) * 8) = vv;
      }
      asm volatile("s_waitcnt lgkmcnt(0)" ::: "memory");
      __builtin_amdgcn_sched_barrier(0);
    }
  }
}

// ---------------------------------------------------------------- 256x256 8-phase GEMM, rev2 (the variant in the 602.9 us best run)
// C[M,N] = A[M,K]*W[N,K]^T + bias.  256x256 tile, 512 thr (8 waves, 2Mx4N),
// BK=64, double-buffered 128 KiB LDS, 1 block/CU.  K templated: all ds_read
// addressing collapses to 8 per-lane byte bases + offset: immediates; global
// addressing is compile-time row*K + uniform t*64.  4 phases/K-tile:
//   ph0: read A(mh0)+B(nh0) | stage A1,B1(t+1) | lgkm(8) | BAR | lgkm0 | 16 MFMA | BAR
//   ph1: read B(nh1)                           | BAR | lgkm0 | 16 MFMA | BAR
//   ph2: read A(mh1)        | stage B0(t+2)    | BAR | lgkm0 | 16 MFMA | BAR
//   ph3:                      stage A0(t+2)    | BAR |         16 MFMA | vmcnt(4) | BAR
template <int EPI, int K>
__global__ __launch_bounds__(512, 2)
void gemm8(const bf16* __restrict__ A, const bf16* __restrict__ W,
           const float* __restrict__ bias, bf16* __restrict__ C, const int N) {
  extern __shared__ bf16 lds[];  // [2 buf][A 16384 | B 16384] elems = 128 KiB
  constexpr int NT = K >> 6;
  static_assert(NT >= 4 && (NT & 1) == 0, "NT even, >=4");

  const int tid = threadIdx.x;
  const int wave = tid >> 6, lane = tid & 63;
  const int wm = wave >> 2, wn = wave & 3;  // 2 x 4 wave grid, 128x64 per wave
  const int cl = lane & 15, hk = lane >> 4;
  const int c7 = cl & 7;
  const int sl8 = (lane & 7) ^ (lane >> 3);

  const int gx = gridDim.x;
  int flat = blockIdx.y * gx + blockIdx.x;
  flat = (flat & 7) * ((gx * gridDim.y) >> 3) + (flat >> 3);
  const int bcol = flat % gx, brow = flat / gx;

  const size_t srow = (size_t)(wave * 8 + (lane >> 3)) * K + sl8 * 8;
  const bf16* pA = A + (size_t)brow * 256 * K + srow;
  const bf16* pW = W + (size_t)bcol * 256 * K + srow;
  bf16* ldsw = lds + wave * 512;

  // per-lane ds_read byte bases [buf][kk]; all frag offsets are immediates
  int bA_[2][2], bB_[2][2];
#pragma unroll
  for (int b_ = 0; b_ < 2; ++b_)
#pragma unroll
    for (int kk = 0; kk < 2; ++kk) {
      const int slot = ((kk * 4 + hk) ^ c7) * 16;
      bA_[b_][kk] = b_ * 65536 + (wm * 128 + cl) * 128 + slot;
      bB_[b_][kk] = b_ * 65536 + 32768 + (wn * 64 + cl) * 128 + slot;
    }

// stage rows [roff, roff+128) at elem-col coff into LDS elem offset dstoff
#define STG2(src, coff, roff, dstoff)                                          \
  do {                                                                         \
    _Pragma("unroll") for (int i_ = 0; i_ < 2; ++i_)                           \
      GLDS16((src) + (coff) + (size_t)((roff) + i_ * 64) * K,                  \
             ldsw + (dstoff) + i_ * 4096);                                     \
  } while (0)

#define LDA8(bf_, kk_, mh_, m_) \
  (*(const bf16x8*)((const char*)lds + bA_[bf_][kk_] + (mh_)*8192 + (m_)*2048))
#define LDB8(bf_, kk_, nh_, n_) \
  (*(const bf16x8*)((const char*)lds + bB_[bf_][kk_] + (nh_)*4096 + (n_)*2048))

#define BAR8 asm volatile("s_barrier" ::: "memory")
#define LGKM0 do { asm volatile("s_waitcnt lgkmcnt(0)" ::: "memory"); \
                   __builtin_amdgcn_sched_barrier(0); } while (0)

  // prologue: tile0 (A0,B0,A1,B1) + B0(1),A0(1); force tile0, 4 loads in flight
  STG2(pA, 0, 0, 0);
  STG2(pW, 0, 0, 16384);
  STG2(pA, 0, 128, 8192);
  STG2(pW, 0, 128, 16384 + 8192);
  STG2(pW, 64, 0, 32768 + 16384);
  STG2(pA, 64, 0, 32768);
  asm volatile("s_waitcnt vmcnt(4)" ::: "memory");
  BAR8;

  f32x4 acc[2][2][4][2] = {};  // [mh][nh][m_][n_]
  bf16x8 af[2][4], b0f[2][2], b1f[2][2];

#pragma unroll 2
  for (int t = 0; t < NT; ++t) {
    const int bf_ = t & 1, nb_ = bf_ ^ 1;
    const int co = t * 64;

    // ---- ph0: read A(mh0)+B(nh0); stage A1(t+1), B1(t+1)
#pragma unroll
    for (int kk = 0; kk < 2; ++kk) {
#pragma unroll
      for (int m_ = 0; m_ < 4; ++m_) af[kk][m_] = LDA8(bf_, kk, 0, m_);
#pragma unroll
      for (int n_ = 0; n_ < 2; ++n_) b0f[kk][n_] = LDB8(bf_, kk, 0, n_);
    }
    if (t + 1 < NT) {
      STG2(pA, co + 64, 128, nb_ * 32768 + 8192);
      STG2(pW, co + 64, 128, nb_ * 32768 + 16384 + 8192);
    }
    asm volatile("s_waitcnt lgkmcnt(8)" ::: "memory");
    BAR8;
    LGKM0;
    __builtin_amdgcn_s_setprio(1);
#pragma unroll
    for (int kk = 0; kk < 2; ++kk)
#pragma unroll
      for (int m_ = 0; m_ < 4; ++m_)
#pragma unroll
        for (int n_ = 0; n_ < 2; ++n_)
          acc[0][0][m_][n_] = MFMA16(af[kk][m_], b0f[kk][n_], acc[0][0][m_][n_]);
    __builtin_amdgcn_s_setprio(0);
    BAR8;

    // ---- ph1: read B(nh1)
#pragma unroll
    for (int kk = 0; kk < 2; ++kk)
#pragma unroll
      for (int n_ = 0; n_ < 2; ++n_) b1f[kk][n_] = LDB8(bf_, kk, 1, n_);
    BAR8;
    LGKM0;
    __builtin_amdgcn_s_setprio(1);
#pragma unroll
    for (int kk = 0; kk < 2; ++kk)
#pragma unroll
      for (int m_ = 0; m_ < 4; ++m_)
#pragma unroll
        for (int n_ = 0; n_ < 2; ++n_)
          acc[0][1][m_][n_] = MFMA16(af[kk][m_], b1f[kk][n_], acc[0][1][m_][n_]);
    __builtin_amdgcn_s_setprio(0);
    BAR8;

    // ---- ph2: read A(mh1); stage B0(t+2)
#pragma unroll
    for (int kk = 0; kk < 2; ++kk)
#pragma unroll
      for (int m_ = 0; m_ < 4; ++m_) af[kk][m_] = LDA8(bf_, kk, 1, m_);
    if (t + 2 < NT) STG2(pW, co + 128, 0, bf_ * 32768 + 16384);
    BAR8;
    LGKM0;
    __builtin_amdgcn_s_setprio(1);
#pragma unroll
    for (int kk = 0; kk < 2; ++kk)
#pragma unroll
      for (int m_ = 0; m_ < 4; ++m_)
#pragma unroll
        for (int n_ = 0; n_ < 2; ++n_)
          acc[1][0][m_][n_] = MFMA16(af[kk][m_], b0f[kk][n_], acc[1][0][m_][n_]);
    __builtin_amdgcn_s_setprio(0);
    BAR8;

    // ---- ph3: stage A0(t+2); MFMA; counted vmcnt
    if (t + 2 < NT) STG2(pA, co + 128, 0, bf_ * 32768);
    BAR8;
    __builtin_amdgcn_s_setprio(1);
#pragma unroll
    for (int kk = 0; kk < 2; ++kk)
#pragma unroll
      for (int m_ = 0; m_ < 4; ++m_)
#pragma unroll
        for (int n_ = 0; n_ < 2; ++n_)
          acc[1][1][m_][n_] = MFMA16(af[kk][m_], b1f[kk][n_], acc[1][1][m_][n_]);
    __builtin_amdgcn_s_setprio(0);
    if (t + 2 < NT) {
      asm volatile("s_waitcnt vmcnt(4)" ::: "memory");
    } else {
      asm volatile("s_waitcnt vmcnt(0)" ::: "memory");
    }
    BAR8;
  }
#undef STG2
#undef LDA8
#undef LDB8
#undef BAR8
#undef LGKM0

  __syncthreads();  // drain before LDS reuse as epilogue scratch

  float bv[2][2];
#pragma unroll
  for (int nh = 0; nh < 2; ++nh)
#pragma unroll
    for (int n_ = 0; n_ < 2; ++n_)
      bv[nh][n_] = bias[bcol * 256 + wn * 64 + nh * 32 + n_ * 16 + cl];

  const int crow0 = brow * 256 + wm * 128;
  const int ccol0 = bcol * 256 + wn * 64;
  bf16* ep = lds + wave * 2304;

#pragma unroll
  for (int mh = 0; mh < 2; ++mh)
#pragma unroll
    for (int m_ = 0; m_ < 4; ++m_) {
#pragma unroll
      for (int nh = 0; nh < 2; ++nh)
#pragma unroll
        for (int n_ = 0; n_ < 2; ++n_)
#pragma unroll
          for (int j = 0; j < 4; ++j) {
            float val = acc[mh][nh][m_][n_][j] + bv[nh][n_];
            if (EPI == 1) val = fmaxf(val, 0.f);
            ep[(hk * 4 + j) * 64 + nh * 32 + n_ * 16 + cl] = (bf16)val;
          }
      asm volatile("s_waitcnt lgkmcnt(0)" ::: "memory");
      __builtin_amdgcn_sched_barrier(0);
#pragma unroll
      for (int i = 0; i < 2; ++i) {
        bf16x8 vv = ((const bf16x8*)ep)[lane + i * 64];
        const int row = crow0 + mh * 64 + m_ * 16 + 8 * i + (lane >> 3);
        *(bf16x8*)(C + (size_t)row * N + ccol0 + (lane & 7) * 8) = vv;
      }
      asm volatile("s_waitcnt lgkmcnt(0)" ::: "memory");
      __builtin_amdgcn_sched_barrier(0);
    }
}

// ---------------------------------------------------------------- flash attention (q == k), strict causal (j < i)
// Swapped QK^T (lane owns q-row); Q pre-scaled by 1/8 (exact); diag/non-diag
// split (wave-uniform); deferred per-lane l; shared P buffer per wave.
// R7: defer-max THR=8 + exp-sum pairwise tree (-9.6us, verified).
// R8: exp2+fma exp path + left-folded max trees (-1.1us).
#define SOFTMAX_PV(sc_, diag_, mreg, lreg, oacc)                                 \
  do {                                                                           \
    if (diag_) {                                                                 \
      _Pragma("unroll") for (int c = 0; c < 4; ++c)                              \
        _Pragma("unroll") for (int j = 0; j < 4; ++j)                            \
          if (c * 16 + hk * 4 + j >= wave * 16 + cl) sc_[c][j] = -1e30f;         \
    }                                                                            \
    float rl_[4];                                                                \
    _Pragma("unroll") for (int c = 0; c < 4; ++c)                                \
      rl_[c] = fmaxf(fmaxf(fmaxf(sc_[c][0], sc_[c][1]), sc_[c][2]), sc_[c][3]);  \
    float rloc_ = fmaxf(fmaxf(fmaxf(rl_[0], rl_[1]), rl_[2]), rl_[3]);           \
    if (!__all(rloc_ <= mreg + 8.0f)) {                                          \
      float rmx_ = fmaxf(rloc_, __shfl_xor(rloc_, 16));                          \
      rmx_ = fmaxf(rmx_, __shfl_xor(rmx_, 32));                                  \
      float mn_ = fmaxf(mreg, rmx_);                                             \
      float sca_ = __expf(mreg - mn_);                                           \
      mreg = mn_;                                                                \
      lreg *= sca_;                                                              \
      float scr_[4];                                                             \
      _Pragma("unroll") for (int j = 0; j < 4; ++j)                              \
        scr_[j] = __shfl(sca_, hk * 4 + j);                                      \
      _Pragma("unroll") for (int c = 0; c < 4; ++c)                              \
        _Pragma("unroll") for (int j = 0; j < 4; ++j) oacc[c][j] *= scr_[j];     \
    }                                                                            \
    const float L2E_ = 1.44269504f;                                              \
    const float mnegL_ = -mreg * L2E_;                                           \
    float psc_[4];                                                               \
    if (diag_) {                                                                 \
      _Pragma("unroll") for (int c = 0; c < 4; ++c) {                            \
        bf16x4 pk_;                                                              \
        float ec_[4];                                                            \
        _Pragma("unroll") for (int j = 0; j < 4; ++j) {                          \
          float e_ = (sc_[c][j] < -1e29f)                                        \
                         ? 0.f : exp2f(fmaf(sc_[c][j], L2E_, mnegL_));           \
          ec_[j] = e_;                                                           \
          pk_[j] = (bf16)e_;                                                     \
        }                                                                        \
        psc_[c] = (ec_[0] + ec_[1]) + (ec_[2] + ec_[3]);                         \
        *(bf16x4*)&Pw[SW(cl, c * 2 + (hk >> 1)) + (hk & 1) * 4] = pk_;           \
      }                                                                          \
    } else {                                                                     \
      _Pragma("unroll") for (int c = 0; c < 4; ++c) {                            \
        bf16x4 pk_;                                                              \
        float ec_[4];                                                            \
        _Pragma("unroll") for (int j = 0; j < 4; ++j) {                          \
          float e_ = exp2f(fmaf(sc_[c][j], L2E_, mnegL_));                       \
          ec_[j] = e_;                                                           \
          pk_[j] = (bf16)e_;                                                     \
        }                                                                        \
        psc_[c] = (ec_[0] + ec_[1]) + (ec_[2] + ec_[3]);                         \
        *(bf16x4*)&Pw[SW(cl, c * 2 + (hk >> 1)) + (hk & 1) * 4] = pk_;           \
      }                                                                          \
    }                                                                            \
    lreg += (psc_[0] + psc_[1]) + (psc_[2] + psc_[3]);                           \
    const bf16x8 pa0_ = *(const bf16x8*)&Pw[SW(cl, hk)];                         \
    const bf16x8 pa1_ = *(const bf16x8*)&Pw[SW(cl, 4 + hk)];                     \
    __builtin_amdgcn_s_setprio(1);                                               \
    _Pragma("unroll") for (int c = 0; c < 4; ++c) {                              \
      const bf16x8 vf0_ = *(const bf16x8*)&Vb[SW(c * 16 + cl, hk)];              \
      const bf16x8 vf1_ = *(const bf16x8*)&Vb[SW(c * 16 + cl, 4 + hk)];          \
      oacc[c] = MFMA16(pa0_, vf0_, oacc[c]);                                     \
      oacc[c] = MFMA16(pa1_, vf1_, oacc[c]);                                     \
    }                                                                            \
    __builtin_amdgcn_s_setprio(0);                                               \
  } while (0)

__global__ __launch_bounds__(256, 3)
void attn_kernel(const bf16* __restrict__ q, const bf16* __restrict__ vT,
                 bf16* __restrict__ out) {
  const int S = 1024, D = 1024;
  // XCD-grouping swizzle: each XCD owns 16 bh values (K/V slice = 4 MB = 1 L2)
  const int f = blockIdx.y * 8 + blockIdx.x;
  const int g = f >> 3, xcd = f & 7;
  const int qa = g >> 4;               // 0..7
  const int bh = xcd * 16 + (g & 15);  // 0..127
  const int qb = 15 - qa;              // 8..15 (> qa always)
  const int b = bh >> 4, h = bh & 15;
  const int tid = threadIdx.x, wave = tid >> 6, lane = tid & 63;

  __shared__ bf16 Ks[2][4096];
  __shared__ bf16 Vt[2][4096];   // staged from vT (swizzled)
  __shared__ bf16 Ps[4][1024];   // per-wave P tile, shared by the two streams

  const bf16* qp = q + (size_t)b * S * D + h * 64;
  const bf16* vp = vT + (size_t)(b * 16 + h) * 64 * 1024;  // [64 d][1024 s]

  const int cl = lane & 15;
  const int hk = lane >> 4;
  const int r0 = hk * 4;
  const int k8 = hk * 8;

  const int ksrow = lane >> 3;
  const int ksslot = (lane & 7) ^ (lane >> 3);

  const int rA = qa * 64 + wave * 16 + cl;
  const int rB = qb * 64 + wave * 16 + cl;
  const bf16x8 qA0 = scale8th(*(const bf16x8*)(qp + (size_t)rA * D + k8));
  const bf16x8 qA1 = scale8th(*(const bf16x8*)(qp + (size_t)rA * D + 32 + k8));
  const bf16x8 qB0 = scale8th(*(const bf16x8*)(qp + (size_t)rB * D + k8));
  const bf16x8 qB1 = scale8th(*(const bf16x8*)(qp + (size_t)rB * D + 32 + k8));

  f32x4 oA[4] = {}, oB[4] = {};
  float mA_ = -1e30f, lA_ = 0.f, mB_ = -1e30f, lB_ = 0.f;

  bf16* Pw = Ps[wave];
  int buf = 0;

#define STAGE_KV(dst_ks, dst_vt, jt_)                                            \
  do {                                                                           \
    _Pragma("unroll") for (int j = 0; j < 2; ++j) {                              \
      int ch = wave * 2 + j;                                                     \
      GLDS16(qp + (size_t)((jt_) * 64 + ch * 8 + ksrow) * D +                    \
                 ((ksslot ^ (ch & 7)) * 8),                                      \
             (dst_ks) + ch * 512);                                               \
      GLDS16(vp + (size_t)(ch * 8 + ksrow) * 1024 + (jt_) * 64 +                 \
                 ((ksslot ^ (ch & 7)) * 8),                                      \
             (dst_vt) + ch * 512);                                               \
    }                                                                            \
  } while (0)

  STAGE_KV(&Ks[0][0], &Vt[0][0], 0);
  __syncthreads();

  for (int jt = 0; jt <= qb; ++jt) {
    const int nxt = buf ^ 1;
    if (jt < qb) STAGE_KV(&Ks[nxt][0], &Vt[nxt][0], jt + 1);

    {
      const bf16* Kb = Ks[buf];
      const bf16* Vb = Vt[buf];
      const bool doA = (jt <= qa);
      const bool diagB = (jt == qb), diagA = (jt == qa);

      // QK^T, shared K-frag loads (Q pre-scaled -> scores already /sqrt(dk))
      f32x4 scB[4], scA[4];
      __builtin_amdgcn_s_setprio(1);
#pragma unroll
      for (int c = 0; c < 4; ++c) {
        int r_ = c * 16 + cl;
        const bf16x8 kf0 = *(const bf16x8*)&Kb[SW(r_, hk)];
        const bf16x8 kf1 = *(const bf16x8*)&Kb[SW(r_, 4 + hk)];
        f32x4 zB = {};
        zB = MFMA16(kf0, qB0, zB);
        zB = MFMA16(kf1, qB1, zB);
        scB[c] = zB;
        if (doA) {
          f32x4 zA = {};
          zA = MFMA16(kf0, qA0, zA);
          zA = MFMA16(kf1, qA1, zA);
          scA[c] = zA;
        }
      }
      __builtin_amdgcn_s_setprio(0);

      SOFTMAX_PV(scB, diagB, mB_, lB_, oB);
      if (doA) SOFTMAX_PV(scA, diagA, mA_, lA_, oA);
    }
    __syncthreads();
    buf = nxt;
  }
#undef STAGE_KV

  // final l reduction (deferred across tiles): sum the 4 row-lanes once
  lA_ += __shfl_xor(lA_, 16);
  lA_ += __shfl_xor(lA_, 32);
  lB_ += __shfl_xor(lB_, 16);
  lB_ += __shfl_xor(lB_, 32);

  bf16* ob = out + (size_t)b * S * D + h * 64;
  const float invA = (lA_ > 0.f) ? 1.f / lA_ : 0.f;  // row 0 -> zeros (zero_pad)
  const float invB = (lB_ > 0.f) ? 1.f / lB_ : 0.f;
#pragma unroll
  for (int j = 0; j < 4; ++j) {
    const float iA = __shfl(invA, hk * 4 + j);
    const float iB = __shfl(invB, hk * 4 + j);
    {
      int row = qa * 64 + wave * 16 + r0 + j;
#pragma unroll
      for (int c = 0; c < 4; ++c)
        ob[(size_t)row * D + c * 16 + cl] = (bf16)(oA[c][j] * iA);
    }
    {
      int row = qb * 64 + wave * 16 + r0 + j;
#pragma unroll
      for (int c = 0; c < 4; ++c)
        ob[(size_t)row * D + c * 16 + cl] = (bf16)(oB[c][j] * iB);
    }
  }
}

// ---------------------------------------------------------------- fused add + layernorm (row = 1024), bf16 in
// R9: producers (Wo / FF2) fuse the residual add; when xin == nullptr the
// sum is already in y1b and this reads one buffer (32 MB -> 21 MB traffic).
__global__ __launch_bounds__(256)
void add_ln(const ushort4* __restrict__ xin, const ushort4* __restrict__ y1b,
            const float* __restrict__ g, const float* __restrict__ bt,
            ushort4* __restrict__ xbf, float4* __restrict__ xout) {
  const int row = blockIdx.x;
  const int tid = threadIdx.x;
  const int wave = tid >> 6, lane = tid & 63;
  const size_t base4 = (size_t)row * 256 + tid;
  ushort4 c4 = y1b[base4];
  float v0, v1, v2, v3;
  if (xin) {
    ushort4 a4 = xin[base4];
    v0 = b2f(a4.x) + b2f(c4.x); v1 = b2f(a4.y) + b2f(c4.y);
    v2 = b2f(a4.z) + b2f(c4.z); v3 = b2f(a4.w) + b2f(c4.w);
  } else {
    v0 = b2f(c4.x); v1 = b2f(c4.y); v2 = b2f(c4.z); v3 = b2f(c4.w);
  }

  float s = v0 + v1 + v2 + v3;
#pragma unroll
  for (int off = 32; off; off >>= 1) s += __shfl_xor(s, off);
  __shared__ float red1[4], red2[4];
  if (lane == 0) red1[wave] = s;
  __syncthreads();
  float mean = (red1[0] + red1[1] + red1[2] + red1[3]) * (1.f / 1024.f);

  float d0 = v0 - mean, d1 = v1 - mean, d2 = v2 - mean, d3 = v3 - mean;
  float vs = d0 * d0 + d1 * d1 + d2 * d2 + d3 * d3;
#pragma unroll
  for (int off = 32; off; off >>= 1) vs += __shfl_xor(vs, off);
  if (lane == 0) red2[wave] = vs;
  __syncthreads();
  float var = (red2[0] + red2[1] + red2[2] + red2[3]) * (1.f / 1024.f);
  float rstd = rsqrtf(var + 1e-5f);

  const int col = tid * 4;
  float4 gg = *(const float4*)(g + col);
  float4 bb = *(const float4*)(bt + col);
  float o0 = d0 * rstd * gg.x + bb.x;
  float o1 = d1 * rstd * gg.y + bb.y;
  float o2 = d2 * rstd * gg.z + bb.z;
  float o3 = d3 * rstd * gg.w + bb.w;
  if (xout) {
    float4 oo; oo.x = o0; oo.y = o1; oo.z = o2; oo.w = o3;
    xout[base4] = oo;
  } else {
    ushort4 ob;
    ob.x = __builtin_bit_cast(unsigned short, (bf16)o0);
    ob.y = __builtin_bit_cast(unsigned short, (bf16)o1);
    ob.z = __builtin_bit_cast(unsigned short, (bf16)o2);
    ob.w = __builtin_bit_cast(unsigned short, (bf16)o3);
    xbf[base4] = ob;
  }
}

// ---------------------------------------------------------------- launch
extern "C" void kernel_launch(void* const* d_in, const int* in_sizes, int n_in,
                              void* d_out, int out_size, void* d_ws, size_t ws_size,
                              hipStream_t stream) {
  const float* qd  = (const float*)d_in[0];
  const float* qa  = (const float*)d_in[1];
  const float* Wk  = (const float*)d_in[2];
  const float* bk  = (const float*)d_in[3];
  const float* Wv  = (const float*)d_in[4];
  const float* bv  = (const float*)d_in[5];
  const float* Wo  = (const float*)d_in[6];
  const float* bo  = (const float*)d_in[7];
  const float* l1g = (const float*)d_in[8];
  const float* l1b = (const float*)d_in[9];
  const float* W1  = (const float*)d_in[10];
  const float* b1  = (const float*)d_in[11];
  const float* W2  = (const float*)d_in[12];
  const float* b2  = (const float*)d_in[13];
  const float* l2g = (const float*)d_in[14];
  const float* l2b = (const float*)d_in[15];

  const size_t DD = 1024 * 1024, DFD = 4096 * 1024, T = 8192;  // tokens
  bf16* wkb = (bf16*)d_ws;          // 3 contiguous D*D weights (wk, wv, wo)
  bf16* wvb = wkb + 2 * DD;
  bf16* wob = wvb + 2 * DD;
  bf16* w1b = wob + 2 * DD;         // 2 contiguous DF*D weights (w1, w2)
  bf16* w2b = w1b + 2 * DFD;
  bf16* regA = w2b + 2 * DFD;       // 33,554,432 bf16 elems region
  bf16* qbf = regA;                 // 8,388,608 each
  bf16* vbf = regA + 8388608;       // V^T layout: [bh][64][1024]
  bf16* abf = regA + 16777216;
  bf16* ff1 = regA;                 // reuse (q/v/attn dead during FFN)
  bf16* xbf = regA + 33554432;
  bf16* ybf = xbf + 8388608;
  bf16* g1b = ybf + 8388608;        // bf16 sum buffer (residual fused in gemm)

  static bool gemm8_attr = false;
  if (!gemm8_attr) {
    (void)hipFuncSetAttribute(reinterpret_cast<const void*>(&gemm8<1, 1024>),
                              hipFuncAttributeMaxDynamicSharedMemorySize, 131072);
    gemm8_attr = true;
  }

  prep<<<dim3(1024, 1, 6), 256, 0, stream>>>(
      (const float4*)qd, (const float4*)qa, (ushort4*)xbf, (ushort4*)ybf,
      (const float4*)Wk, (const float4*)Wv, (const float4*)Wo,
      (const float4*)W1, (const float4*)W2,
      (ushort4*)wkb, (ushort4*)w1b, (int)(2 * DD / 4), (int)(2 * DFD / 4));

  for (int l = 0; l < 2; ++l) {
    // q/k projection (z=0, row-major) and v projection (z=1, per-head transposed)
    gemm_s<0, 1, 0><<<dim3(8, 64, 2), 256, 0, stream>>>(
        xbf, wkb + l * DD, bk + l * 1024, qbf,
        ybf, wvb + l * DD, bv + l * 1024, vbf, 1024, 1024);
    attn_kernel<<<dim3(8, 128), 256, 0, stream>>>(qbf, vbf, abf);
    // Wo projection with fused residual add (reads xbf tile, writes sum)
    gemm_s<0, 0, 1><<<dim3(8, 64), 256, 0, stream>>>(
        abf, wob + l * DD, bo + l * 1024, g1b, xbf, nullptr, nullptr, nullptr, 1024, 1024);
    add_ln<<<T, 256, 0, stream>>>(nullptr, (const ushort4*)g1b,
                                  l1g + l * 1024, l1b + l * 1024,
                                  (ushort4*)xbf, nullptr);
    gemm8<1, 1024><<<dim3(16, 32), 512, 131072, stream>>>(
        xbf, w1b + l * DFD, b1 + l * 4096, ff1, 4096);
    // FF2 with fused residual add
    gemm_s<0, 0, 1><<<dim3(8, 64), 256, 0, stream>>>(
        ff1, w2b + l * DFD, b2 + l * 1024, g1b, xbf, nullptr, nullptr, nullptr, 1024, 4096);
    const bool last = (l == 1);
    add_ln<<<T, 256, 0, stream>>>(nullptr, (const ushort4*)g1b,
                                  l2g + l * 1024, l2b + l * 1024,
                                  (ushort4*)xbf, last ? (float4*)d_out : nullptr);
  }
  (void)in_sizes; (void)n_in; (void)out_size; (void)ws_size;
}

// Round 10
// 590.091 us; speedup vs baseline: 1.0265x; 1.0265x over previous
//
#include <hip/hip_runtime.h>

using bf16   = __bf16;
using bf16x4 = __attribute__((ext_vector_type(4))) __bf16;
using bf16x8 = __attribute__((ext_vector_type(8))) __bf16;
using f32x4  = __attribute__((ext_vector_type(4))) float;

#define GLDS16(g, l)                                                            \
  __builtin_amdgcn_global_load_lds(                                             \
      (__attribute__((address_space(1))) void*)(g),                             \
      (__attribute__((address_space(3))) void*)(l), 16, 0, 0)

#define MFMA16(a, b, c) __builtin_amdgcn_mfma_f32_16x16x32_bf16(a, b, c, 0, 0, 0)

// XOR swizzle: row r, 8-elem slot s (0..7) -> elem offset within a [*][64] tile (attn)
__device__ __forceinline__ int SW(int r, int s) {
  return r * 64 + (((s ^ (r & 7) ^ ((r >> 3) & 7)) & 7) << 3);
}

__device__ __forceinline__ float b2f(unsigned short u) {
  return (float)__builtin_bit_cast(bf16, u);
}

// exact: x/8 is an exponent decrement in bf16 (no mantissa change here)
__device__ __forceinline__ bf16x8 scale8th(bf16x8 v) {
  bf16x8 r;
#pragma unroll
  for (int i = 0; i < 8; ++i) r[i] = (bf16)((float)v[i] * 0.125f);
  return r;
}

// ---------------------------------------------------------------- prep: one dispatch for init_pe (z=0) + 5 weight cvts (z=1..5)
// z=0: xbf = q+pe, ybf = qa+pe (bf16 residual stream), grid-stride
// z>=1: fp32 -> bf16 weight converts
__global__ __launch_bounds__(256)
void prep(const float4* __restrict__ qd, const float4* __restrict__ qa,
          ushort4* __restrict__ xbf, ushort4* __restrict__ ybf,
          const float4* __restrict__ s0, const float4* __restrict__ s1,
          const float4* __restrict__ s2, const float4* __restrict__ s3,
          const float4* __restrict__ s4,
          ushort4* __restrict__ dDD, ushort4* __restrict__ dDF,
          int n4dd, int n4df) {
  const int z = blockIdx.z;
  if (z == 0) {
    const int n4 = 8 * 1024 * 1024 / 4;  // B*S*D / 4
    for (int i = blockIdx.x * 256 + threadIdx.x; i < n4; i += gridDim.x * 256) {
      int d4 = (i & 255) * 4;          // feature index 0..1023 step 4
      int ss = (i >> 8) & 1023;        // position
      const float c = -0.0089944730195177f;  // -ln(10000)/1024
      float a0 = (float)ss * __expf((float)d4 * c);
      float a1 = (float)ss * __expf((float)(d4 + 2) * c);
      float p0 = sinf(a0), p1 = cosf(a0), p2 = sinf(a1), p3 = cosf(a1);
      float4 q4 = qd[i], y4 = qa[i];
      ushort4 xb, yb;
      xb.x = __builtin_bit_cast(unsigned short, (bf16)(q4.x + p0));
      xb.y = __builtin_bit_cast(unsigned short, (bf16)(q4.y + p1));
      xb.z = __builtin_bit_cast(unsigned short, (bf16)(q4.z + p2));
      xb.w = __builtin_bit_cast(unsigned short, (bf16)(q4.w + p3));
      yb.x = __builtin_bit_cast(unsigned short, (bf16)(y4.x + p0));
      yb.y = __builtin_bit_cast(unsigned short, (bf16)(y4.y + p1));
      yb.z = __builtin_bit_cast(unsigned short, (bf16)(y4.z + p2));
      yb.w = __builtin_bit_cast(unsigned short, (bf16)(y4.w + p3));
      xbf[i] = xb; ybf[i] = yb;
    }
  } else {
    const int w = z - 1;
    const float4* s = (w == 0) ? s0 : (w == 1) ? s1 : (w == 2) ? s2
                                    : (w == 3) ? s3 : s4;
    ushort4* dd = (w < 3) ? dDD + (size_t)w * n4dd : dDF + (size_t)(w - 3) * n4df;
    const int n4 = (w < 3) ? n4dd : n4df;
    for (int i = blockIdx.x * 256 + threadIdx.x; i < n4; i += gridDim.x * 256) {
      float4 v = s[i];
      ushort4 o;
      o.x = __builtin_bit_cast(unsigned short, (bf16)v.x);
      o.y = __builtin_bit_cast(unsigned short, (bf16)v.y);
      o.z = __builtin_bit_cast(unsigned short, (bf16)v.z);
      o.w = __builtin_bit_cast(unsigned short, (bf16)v.w);
      dd[i] = o;
    }
  }
}

// ---------------------------------------------------------------- m97-faithful GEMM (R11: 885 TF, at structure ceiling)
// C[M,N] = A[M,K]*W[N,K]^T + bias.  128x128 tile, 256 thr (4 waves, 2x2), BK=64,
// single-buffered 32 KiB LDS, 4 blocks/CU TLP. Swizzle: LDS[r][s]=G[r][s^(r&7)].
// EPI: 0 bf16, 1 bf16+relu.
// MODE: 0 plain; 1 pair (z selects operand set; z=1 writes C TRANSPOSED per
//       head: C1[bh][d=0..63][s=0..1023], for attention V).
template <int EPI, int MODE>
__global__ __launch_bounds__(256, 4)
void gemm_s(const bf16* __restrict__ A0, const bf16* __restrict__ W0,
            const float* __restrict__ b0, void* __restrict__ C0,
            const bf16* __restrict__ A1, const bf16* __restrict__ W1,
            const float* __restrict__ b1, void* __restrict__ C1,
            const int N, const int K) {
  __shared__ bf16 L[2][128 * 64];  // [0=A,1=B], 32 KiB

  const int tid = threadIdx.x;
  const int wave = tid >> 6, lane = tid & 63;
  const int wm = wave >> 1, wn = wave & 1;   // 2 x 2 wave grid, 64x64 per wave
  const int cl = lane & 15, hk = lane >> 4;

  // XCD-aware bijective block swizzle (nwg divisible by 8 for all our grids)
  const int gx = gridDim.x;
  int flat = blockIdx.y * gx + blockIdx.x;
  flat = (flat & 7) * ((gx * gridDim.y) >> 3) + (flat >> 3);
  const int bcol = flat % gx, brow = flat / gx;
  const int z = (MODE == 0) ? 0 : blockIdx.z;

  const bf16* A = (MODE == 1 && z) ? A1 : A0;
  const bf16* W = (MODE == 1 && z) ? W1 : W0;
  const float* bias = (MODE == 1 && z) ? b1 : b0;
  void* C = (MODE == 1 && z) ? C1 : C0;

  const bf16* Ablk = A + (size_t)brow * 128 * K;
  const bf16* Wblk = W + (size_t)bcol * 128 * K;

  const int strow8 = lane >> 3;
  const int sl8 = (lane & 7) ^ (lane >> 3);

#define STAGE(kt)                                                               \
  do {                                                                          \
    _Pragma("unroll") for (int i_ = 0; i_ < 4; ++i_) {                          \
      int r0_ = i_ * 32 + wave * 8;                                             \
      GLDS16(Ablk + (size_t)(r0_ + strow8) * K + (size_t)(kt) * 64 + sl8 * 8,   \
             &L[0][r0_ * 64]);                                                  \
      GLDS16(Wblk + (size_t)(r0_ + strow8) * K + (size_t)(kt) * 64 + sl8 * 8,   \
             &L[1][r0_ * 64]);                                                  \
    }                                                                           \
  } while (0)

#define RD(reg, r_, kk_) \
  (*(const bf16x8*)&L[reg][(r_) * 64 + ((((kk_) * 4 + hk) ^ (cl & 7)) * 8)])

  f32x4 acc[4][4] = {};
  const int NT = K >> 6;

  for (int t = 0; t < NT; ++t) {
    STAGE(t);
    __syncthreads();
#pragma unroll
    for (int kk = 0; kk < 2; ++kk) {
      bf16x8 a4[4], b4[4];
#pragma unroll
      for (int m = 0; m < 4; ++m) a4[m] = RD(0, wm * 64 + m * 16 + cl, kk);
#pragma unroll
      for (int n = 0; n < 4; ++n) b4[n] = RD(1, wn * 64 + n * 16 + cl, kk);
      __builtin_amdgcn_s_setprio(1);
#pragma unroll
      for (int m = 0; m < 4; ++m)
#pragma unroll
        for (int n = 0; n < 4; ++n)
          acc[m][n] = MFMA16(a4[m], b4[n], acc[m][n]);
      __builtin_amdgcn_s_setprio(0);
    }
    __syncthreads();
  }
#undef STAGE
#undef RD

  float bv[4];
#pragma unroll
  for (int n = 0; n < 4; ++n)
    bv[n] = bias[bcol * 128 + wn * 64 + n * 16 + cl];

  const int crow0 = brow * 128 + wm * 64;
  const int ccol0 = bcol * 128 + wn * 64;
  char* esmem = (char*)(&L[0][0]) + wave * 4608;

  if (MODE == 1 && z == 1) {
    // V^T epilogue: C1[bh][d][s]
    bf16* ep = (bf16*)esmem;
    const int h_ = ccol0 >> 6;
#pragma unroll
    for (int mp = 0; mp < 2; ++mp) {
#pragma unroll
      for (int mb = 0; mb < 2; ++mb) {
        int m = mp * 2 + mb;
#pragma unroll
        for (int n = 0; n < 4; ++n) {
          bf16x4 w4;
#pragma unroll
          for (int j = 0; j < 4; ++j) w4[j] = (bf16)(acc[m][n][j] + bv[n]);
          *(bf16x4*)&ep[(n * 16 + cl) * 36 + mb * 16 + hk * 4] = w4;
        }
      }
      asm volatile("s_waitcnt lgkmcnt(0)" ::: "memory");
      __builtin_amdgcn_sched_barrier(0);
      {
        const int t0 = crow0 + mp * 32;
        const int b_ = t0 >> 10, s_ = t0 & 1023;
        bf16* dst = (bf16*)C + ((size_t)(b_ * 16 + h_) * 64 + lane) * 1024 + s_;
        const bf16* src = &ep[lane * 36];
#pragma unroll
        for (int i = 0; i < 4; ++i)
          *(bf16x8*)&dst[i * 8] = *(const bf16x8*)&src[i * 8];
      }
      asm volatile("s_waitcnt lgkmcnt(0)" ::: "memory");
      __builtin_amdgcn_sched_barrier(0);
    }
  } else {
#pragma unroll
    for (int m = 0; m < 4; ++m) {
      bf16* ep = (bf16*)esmem;
#pragma unroll
      for (int n = 0; n < 4; ++n)
#pragma unroll
        for (int j = 0; j < 4; ++j) {
          float val = acc[m][n][j] + bv[n];
          if (EPI == 1) val = fmaxf(val, 0.f);
          ep[(hk * 4 + j) * 64 + n * 16 + cl] = (bf16)val;
        }
      asm volatile("s_waitcnt lgkmcnt(0)" ::: "memory");
      __builtin_amdgcn_sched_barrier(0);
#pragma unroll
      for (int i = 0; i < 2; ++i) {
        bf16x8 vv = ((const bf16x8*)ep)[lane + i * 64];
        const int row = crow0 + m * 16 + 8 * i + (lane >> 3);
        *(bf16x8*)((bf16*)C + (size_t)row * N + ccol0 + (lane & 7) * 8) = vv;
      }
      asm volatile("s_waitcnt lgkmcnt(0)" ::: "memory");
      __builtin_amdgcn_sched_barrier(0);
    }
  }
}

// ---------------------------------------------------------------- 256x256 8-phase GEMM, rev2 (the variant in the 602.9 us best run)
// C[M,N] = A[M,K]*W[N,K]^T + bias.  256x256 tile, 512 thr (8 waves, 2Mx4N),
// BK=64, double-buffered 128 KiB LDS, 1 block/CU.  K templated: all ds_read
// addressing collapses to 8 per-lane byte bases + offset: immediates; global
// addressing is compile-time row*K + uniform t*64.  4 phases/K-tile:
//   ph0: read A(mh0)+B(nh0) | stage A1,B1(t+1) | lgkm(8) | BAR | lgkm0 | 16 MFMA | BAR
//   ph1: read B(nh1)                           | BAR | lgkm0 | 16 MFMA | BAR
//   ph2: read A(mh1)        | stage B0(t+2)    | BAR | lgkm0 | 16 MFMA | BAR
//   ph3:                      stage A0(t+2)    | BAR |         16 MFMA | vmcnt(4) | BAR
template <int EPI, int K>
__global__ __launch_bounds__(512, 2)
void gemm8(const bf16* __restrict__ A, const bf16* __restrict__ W,
           const float* __restrict__ bias, bf16* __restrict__ C, const int N) {
  extern __shared__ bf16 lds[];  // [2 buf][A 16384 | B 16384] elems = 128 KiB
  constexpr int NT = K >> 6;
  static_assert(NT >= 4 && (NT & 1) == 0, "NT even, >=4");

  const int tid = threadIdx.x;
  const int wave = tid >> 6, lane = tid & 63;
  const int wm = wave >> 2, wn = wave & 3;  // 2 x 4 wave grid, 128x64 per wave
  const int cl = lane & 15, hk = lane >> 4;
  const int c7 = cl & 7;
  const int sl8 = (lane & 7) ^ (lane >> 3);

  const int gx = gridDim.x;
  int flat = blockIdx.y * gx + blockIdx.x;
  flat = (flat & 7) * ((gx * gridDim.y) >> 3) + (flat >> 3);
  const int bcol = flat % gx, brow = flat / gx;

  const size_t srow = (size_t)(wave * 8 + (lane >> 3)) * K + sl8 * 8;
  const bf16* pA = A + (size_t)brow * 256 * K + srow;
  const bf16* pW = W + (size_t)bcol * 256 * K + srow;
  bf16* ldsw = lds + wave * 512;

  // per-lane ds_read byte bases [buf][kk]; all frag offsets are immediates
  int bA_[2][2], bB_[2][2];
#pragma unroll
  for (int b_ = 0; b_ < 2; ++b_)
#pragma unroll
    for (int kk = 0; kk < 2; ++kk) {
      const int slot = ((kk * 4 + hk) ^ c7) * 16;
      bA_[b_][kk] = b_ * 65536 + (wm * 128 + cl) * 128 + slot;
      bB_[b_][kk] = b_ * 65536 + 32768 + (wn * 64 + cl) * 128 + slot;
    }

// stage rows [roff, roff+128) at elem-col coff into LDS elem offset dstoff
#define STG2(src, coff, roff, dstoff)                                          \
  do {                                                                         \
    _Pragma("unroll") for (int i_ = 0; i_ < 2; ++i_)                           \
      GLDS16((src) + (coff) + (size_t)((roff) + i_ * 64) * K,                  \
             ldsw + (dstoff) + i_ * 4096);                                     \
  } while (0)

#define LDA8(bf_, kk_, mh_, m_) \
  (*(const bf16x8*)((const char*)lds + bA_[bf_][kk_] + (mh_)*8192 + (m_)*2048))
#define LDB8(bf_, kk_, nh_, n_) \
  (*(const bf16x8*)((const char*)lds + bB_[bf_][kk_] + (nh_)*4096 + (n_)*2048))

#define BAR8 asm volatile("s_barrier" ::: "memory")
#define LGKM0 do { asm volatile("s_waitcnt lgkmcnt(0)" ::: "memory"); \
                   __builtin_amdgcn_sched_barrier(0); } while (0)

  // prologue: tile0 (A0,B0,A1,B1) + B0(1),A0(1); force tile0, 4 loads in flight
  STG2(pA, 0, 0, 0);
  STG2(pW, 0, 0, 16384);
  STG2(pA, 0, 128, 8192);
  STG2(pW, 0, 128, 16384 + 8192);
  STG2(pW, 64, 0, 32768 + 16384);
  STG2(pA, 64, 0, 32768);
  asm volatile("s_waitcnt vmcnt(4)" ::: "memory");
  BAR8;

  f32x4 acc[2][2][4][2] = {};  // [mh][nh][m_][n_]
  bf16x8 af[2][4], b0f[2][2], b1f[2][2];

#pragma unroll 2
  for (int t = 0; t < NT; ++t) {
    const int bf_ = t & 1, nb_ = bf_ ^ 1;
    const int co = t * 64;

    // ---- ph0: read A(mh0)+B(nh0); stage A1(t+1), B1(t+1)
#pragma unroll
    for (int kk = 0; kk < 2; ++kk) {
#pragma unroll
      for (int m_ = 0; m_ < 4; ++m_) af[kk][m_] = LDA8(bf_, kk, 0, m_);
#pragma unroll
      for (int n_ = 0; n_ < 2; ++n_) b0f[kk][n_] = LDB8(bf_, kk, 0, n_);
    }
    if (t + 1 < NT) {
      STG2(pA, co + 64, 128, nb_ * 32768 + 8192);
      STG2(pW, co + 64, 128, nb_ * 32768 + 16384 + 8192);
    }
    asm volatile("s_waitcnt lgkmcnt(8)" ::: "memory");
    BAR8;
    LGKM0;
    __builtin_amdgcn_s_setprio(1);
#pragma unroll
    for (int kk = 0; kk < 2; ++kk)
#pragma unroll
      for (int m_ = 0; m_ < 4; ++m_)
#pragma unroll
        for (int n_ = 0; n_ < 2; ++n_)
          acc[0][0][m_][n_] = MFMA16(af[kk][m_], b0f[kk][n_], acc[0][0][m_][n_]);
    __builtin_amdgcn_s_setprio(0);
    BAR8;

    // ---- ph1: read B(nh1)
#pragma unroll
    for (int kk = 0; kk < 2; ++kk)
#pragma unroll
      for (int n_ = 0; n_ < 2; ++n_) b1f[kk][n_] = LDB8(bf_, kk, 1, n_);
    BAR8;
    LGKM0;
    __builtin_amdgcn_s_setprio(1);
#pragma unroll
    for (int kk = 0; kk < 2; ++kk)
#pragma unroll
      for (int m_ = 0; m_ < 4; ++m_)
#pragma unroll
        for (int n_ = 0; n_ < 2; ++n_)
          acc[0][1][m_][n_] = MFMA16(af[kk][m_], b1f[kk][n_], acc[0][1][m_][n_]);
    __builtin_amdgcn_s_setprio(0);
    BAR8;

    // ---- ph2: read A(mh1); stage B0(t+2)
#pragma unroll
    for (int kk = 0; kk < 2; ++kk)
#pragma unroll
      for (int m_ = 0; m_ < 4; ++m_) af[kk][m_] = LDA8(bf_, kk, 1, m_);
    if (t + 2 < NT) STG2(pW, co + 128, 0, bf_ * 32768 + 16384);
    BAR8;
    LGKM0;
    __builtin_amdgcn_s_setprio(1);
#pragma unroll
    for (int kk = 0; kk < 2; ++kk)
#pragma unroll
      for (int m_ = 0; m_ < 4; ++m_)
#pragma unroll
        for (int n_ = 0; n_ < 2; ++n_)
          acc[1][0][m_][n_] = MFMA16(af[kk][m_], b0f[kk][n_], acc[1][0][m_][n_]);
    __builtin_amdgcn_s_setprio(0);
    BAR8;

    // ---- ph3: stage A0(t+2); MFMA; counted vmcnt
    if (t + 2 < NT) STG2(pA, co + 128, 0, bf_ * 32768);
    BAR8;
    __builtin_amdgcn_s_setprio(1);
#pragma unroll
    for (int kk = 0; kk < 2; ++kk)
#pragma unroll
      for (int m_ = 0; m_ < 4; ++m_)
#pragma unroll
        for (int n_ = 0; n_ < 2; ++n_)
          acc[1][1][m_][n_] = MFMA16(af[kk][m_], b1f[kk][n_], acc[1][1][m_][n_]);
    __builtin_amdgcn_s_setprio(0);
    if (t + 2 < NT) {
      asm volatile("s_waitcnt vmcnt(4)" ::: "memory");
    } else {
      asm volatile("s_waitcnt vmcnt(0)" ::: "memory");
    }
    BAR8;
  }
#undef STG2
#undef LDA8
#undef LDB8
#undef BAR8
#undef LGKM0

  __syncthreads();  // drain before LDS reuse as epilogue scratch

  float bv[2][2];
#pragma unroll
  for (int nh = 0; nh < 2; ++nh)
#pragma unroll
    for (int n_ = 0; n_ < 2; ++n_)
      bv[nh][n_] = bias[bcol * 256 + wn * 64 + nh * 32 + n_ * 16 + cl];

  const int crow0 = brow * 256 + wm * 128;
  const int ccol0 = bcol * 256 + wn * 64;
  bf16* ep = lds + wave * 2304;

#pragma unroll
  for (int mh = 0; mh < 2; ++mh)
#pragma unroll
    for (int m_ = 0; m_ < 4; ++m_) {
#pragma unroll
      for (int nh = 0; nh < 2; ++nh)
#pragma unroll
        for (int n_ = 0; n_ < 2; ++n_)
#pragma unroll
          for (int j = 0; j < 4; ++j) {
            float val = acc[mh][nh][m_][n_][j] + bv[nh][n_];
            if (EPI == 1) val = fmaxf(val, 0.f);
            ep[(hk * 4 + j) * 64 + nh * 32 + n_ * 16 + cl] = (bf16)val;
          }
      asm volatile("s_waitcnt lgkmcnt(0)" ::: "memory");
      __builtin_amdgcn_sched_barrier(0);
#pragma unroll
      for (int i = 0; i < 2; ++i) {
        bf16x8 vv = ((const bf16x8*)ep)[lane + i * 64];
        const int row = crow0 + mh * 64 + m_ * 16 + 8 * i + (lane >> 3);
        *(bf16x8*)(C + (size_t)row * N + ccol0 + (lane & 7) * 8) = vv;
      }
      asm volatile("s_waitcnt lgkmcnt(0)" ::: "memory");
      __builtin_amdgcn_sched_barrier(0);
    }
}

// ---------------------------------------------------------------- flash attention (q == k), strict causal (j < i)
// Swapped QK^T (lane owns q-row); Q pre-scaled by 1/8 (exact); diag/non-diag
// split (wave-uniform); deferred per-lane l; shared P buffer per wave.
// R7: defer-max THR=8 + exp-sum pairwise tree (-9.6us, verified).
// R8: exp2+fma exp path + left-folded max trees (-1.1us).
// R9's residual-into-GEMM fusion regressed (+13.7us, absmax 2x) — reverted.
#define SOFTMAX_PV(sc_, diag_, mreg, lreg, oacc)                                 \
  do {                                                                           \
    if (diag_) {                                                                 \
      _Pragma("unroll") for (int c = 0; c < 4; ++c)                              \
        _Pragma("unroll") for (int j = 0; j < 4; ++j)                            \
          if (c * 16 + hk * 4 + j >= wave * 16 + cl) sc_[c][j] = -1e30f;         \
    }                                                                            \
    float rl_[4];                                                                \
    _Pragma("unroll") for (int c = 0; c < 4; ++c)                                \
      rl_[c] = fmaxf(fmaxf(fmaxf(sc_[c][0], sc_[c][1]), sc_[c][2]), sc_[c][3]);  \
    float rloc_ = fmaxf(fmaxf(fmaxf(rl_[0], rl_[1]), rl_[2]), rl_[3]);           \
    if (!__all(rloc_ <= mreg + 8.0f)) {                                          \
      float rmx_ = fmaxf(rloc_, __shfl_xor(rloc_, 16));                          \
      rmx_ = fmaxf(rmx_, __shfl_xor(rmx_, 32));                                  \
      float mn_ = fmaxf(mreg, rmx_);                                             \
      float sca_ = __expf(mreg - mn_);                                           \
      mreg = mn_;                                                                \
      lreg *= sca_;                                                              \
      float scr_[4];                                                             \
      _Pragma("unroll") for (int j = 0; j < 4; ++j)                              \
        scr_[j] = __shfl(sca_, hk * 4 + j);                                      \
      _Pragma("unroll") for (int c = 0; c < 4; ++c)                              \
        _Pragma("unroll") for (int j = 0; j < 4; ++j) oacc[c][j] *= scr_[j];     \
    }                                                                            \
    const float L2E_ = 1.44269504f;                                              \
    const float mnegL_ = -mreg * L2E_;                                           \
    float psc_[4];                                                               \
    if (diag_) {                                                                 \
      _Pragma("unroll") for (int c = 0; c < 4; ++c) {                            \
        bf16x4 pk_;                                                              \
        float ec_[4];                                                            \
        _Pragma("unroll") for (int j = 0; j < 4; ++j) {                          \
          float e_ = (sc_[c][j] < -1e29f)                                        \
                         ? 0.f : exp2f(fmaf(sc_[c][j], L2E_, mnegL_));           \
          ec_[j] = e_;                                                           \
          pk_[j] = (bf16)e_;                                                     \
        }                                                                        \
        psc_[c] = (ec_[0] + ec_[1]) + (ec_[2] + ec_[3]);                         \
        *(bf16x4*)&Pw[SW(cl, c * 2 + (hk >> 1)) + (hk & 1) * 4] = pk_;           \
      }                                                                          \
    } else {                                                                     \
      _Pragma("unroll") for (int c = 0; c < 4; ++c) {                            \
        bf16x4 pk_;                                                              \
        float ec_[4];                                                            \
        _Pragma("unroll") for (int j = 0; j < 4; ++j) {                          \
          float e_ = exp2f(fmaf(sc_[c][j], L2E_, mnegL_));                       \
          ec_[j] = e_;                                                           \
          pk_[j] = (bf16)e_;                                                     \
        }                                                                        \
        psc_[c] = (ec_[0] + ec_[1]) + (ec_[2] + ec_[3]);                         \
        *(bf16x4*)&Pw[SW(cl, c * 2 + (hk >> 1)) + (hk & 1) * 4] = pk_;           \
      }                                                                          \
    }                                                                            \
    lreg += (psc_[0] + psc_[1]) + (psc_[2] + psc_[3]);                           \
    const bf16x8 pa0_ = *(const bf16x8*)&Pw[SW(cl, hk)];                         \
    const bf16x8 pa1_ = *(const bf16x8*)&Pw[SW(cl, 4 + hk)];                     \
    __builtin_amdgcn_s_setprio(1);                                               \
    _Pragma("unroll") for (int c = 0; c < 4; ++c) {                              \
      const bf16x8 vf0_ = *(const bf16x8*)&Vb[SW(c * 16 + cl, hk)];              \
      const bf16x8 vf1_ = *(const bf16x8*)&Vb[SW(c * 16 + cl, 4 + hk)];          \
      oacc[c] = MFMA16(pa0_, vf0_, oacc[c]);                                     \
      oacc[c] = MFMA16(pa1_, vf1_, oacc[c]);                                     \
    }                                                                            \
    __builtin_amdgcn_s_setprio(0);                                               \
  } while (0)

__global__ __launch_bounds__(256, 3)
void attn_kernel(const bf16* __restrict__ q, const bf16* __restrict__ vT,
                 bf16* __restrict__ out) {
  const int S = 1024, D = 1024;
  // XCD-grouping swizzle: each XCD owns 16 bh values (K/V slice = 4 MB = 1 L2)
  const int f = blockIdx.y * 8 + blockIdx.x;
  const int g = f >> 3, xcd = f & 7;
  const int qa = g >> 4;               // 0..7
  const int bh = xcd * 16 + (g & 15);  // 0..127
  const int qb = 15 - qa;              // 8..15 (> qa always)
  const int b = bh >> 4, h = bh & 15;
  const int tid = threadIdx.x, wave = tid >> 6, lane = tid & 63;

  __shared__ bf16 Ks[2][4096];
  __shared__ bf16 Vt[2][4096];   // staged from vT (swizzled)
  __shared__ bf16 Ps[4][1024];   // per-wave P tile, shared by the two streams

  const bf16* qp = q + (size_t)b * S * D + h * 64;
  const bf16* vp = vT + (size_t)(b * 16 + h) * 64 * 1024;  // [64 d][1024 s]

  const int cl = lane & 15;
  const int hk = lane >> 4;
  const int r0 = hk * 4;
  const int k8 = hk * 8;

  const int ksrow = lane >> 3;
  const int ksslot = (lane & 7) ^ (lane >> 3);

  const int rA = qa * 64 + wave * 16 + cl;
  const int rB = qb * 64 + wave * 16 + cl;
  const bf16x8 qA0 = scale8th(*(const bf16x8*)(qp + (size_t)rA * D + k8));
  const bf16x8 qA1 = scale8th(*(const bf16x8*)(qp + (size_t)rA * D + 32 + k8));
  const bf16x8 qB0 = scale8th(*(const bf16x8*)(qp + (size_t)rB * D + k8));
  const bf16x8 qB1 = scale8th(*(const bf16x8*)(qp + (size_t)rB * D + 32 + k8));

  f32x4 oA[4] = {}, oB[4] = {};
  float mA_ = -1e30f, lA_ = 0.f, mB_ = -1e30f, lB_ = 0.f;

  bf16* Pw = Ps[wave];
  int buf = 0;

#define STAGE_KV(dst_ks, dst_vt, jt_)                                            \
  do {                                                                           \
    _Pragma("unroll") for (int j = 0; j < 2; ++j) {                              \
      int ch = wave * 2 + j;                                                     \
      GLDS16(qp + (size_t)((jt_) * 64 + ch * 8 + ksrow) * D +                    \
                 ((ksslot ^ (ch & 7)) * 8),                                      \
             (dst_ks) + ch * 512);                                               \
      GLDS16(vp + (size_t)(ch * 8 + ksrow) * 1024 + (jt_) * 64 +                 \
                 ((ksslot ^ (ch & 7)) * 8),                                      \
             (dst_vt) + ch * 512);                                               \
    }                                                                            \
  } while (0)

  STAGE_KV(&Ks[0][0], &Vt[0][0], 0);
  __syncthreads();

  for (int jt = 0; jt <= qb; ++jt) {
    const int nxt = buf ^ 1;
    if (jt < qb) STAGE_KV(&Ks[nxt][0], &Vt[nxt][0], jt + 1);

    {
      const bf16* Kb = Ks[buf];
      const bf16* Vb = Vt[buf];
      const bool doA = (jt <= qa);
      const bool diagB = (jt == qb), diagA = (jt == qa);

      // QK^T, shared K-frag loads (Q pre-scaled -> scores already /sqrt(dk))
      f32x4 scB[4], scA[4];
      __builtin_amdgcn_s_setprio(1);
#pragma unroll
      for (int c = 0; c < 4; ++c) {
        int r_ = c * 16 + cl;
        const bf16x8 kf0 = *(const bf16x8*)&Kb[SW(r_, hk)];
        const bf16x8 kf1 = *(const bf16x8*)&Kb[SW(r_, 4 + hk)];
        f32x4 zB = {};
        zB = MFMA16(kf0, qB0, zB);
        zB = MFMA16(kf1, qB1, zB);
        scB[c] = zB;
        if (doA) {
          f32x4 zA = {};
          zA = MFMA16(kf0, qA0, zA);
          zA = MFMA16(kf1, qA1, zA);
          scA[c] = zA;
        }
      }
      __builtin_amdgcn_s_setprio(0);

      SOFTMAX_PV(scB, diagB, mB_, lB_, oB);
      if (doA) SOFTMAX_PV(scA, diagA, mA_, lA_, oA);
    }
    __syncthreads();
    buf = nxt;
  }
#undef STAGE_KV

  // final l reduction (deferred across tiles): sum the 4 row-lanes once
  lA_ += __shfl_xor(lA_, 16);
  lA_ += __shfl_xor(lA_, 32);
  lB_ += __shfl_xor(lB_, 16);
  lB_ += __shfl_xor(lB_, 32);

  bf16* ob = out + (size_t)b * S * D + h * 64;
  const float invA = (lA_ > 0.f) ? 1.f / lA_ : 0.f;  // row 0 -> zeros (zero_pad)
  const float invB = (lB_ > 0.f) ? 1.f / lB_ : 0.f;
#pragma unroll
  for (int j = 0; j < 4; ++j) {
    const float iA = __shfl(invA, hk * 4 + j);
    const float iB = __shfl(invB, hk * 4 + j);
    {
      int row = qa * 64 + wave * 16 + r0 + j;
#pragma unroll
      for (int c = 0; c < 4; ++c)
        ob[(size_t)row * D + c * 16 + cl] = (bf16)(oA[c][j] * iA);
    }
    {
      int row = qb * 64 + wave * 16 + r0 + j;
#pragma unroll
      for (int c = 0; c < 4; ++c)
        ob[(size_t)row * D + c * 16 + cl] = (bf16)(oB[c][j] * iB);
    }
  }
}

// ---------------------------------------------------------------- fused add + layernorm (row = 1024), bf16 in
__global__ __launch_bounds__(256)
void add_ln(const ushort4* __restrict__ xin, const ushort4* __restrict__ y1b,
            const float* __restrict__ g, const float* __restrict__ bt,
            ushort4* __restrict__ xbf, float4* __restrict__ xout) {
  const int row = blockIdx.x;
  const int tid = threadIdx.x;
  const int wave = tid >> 6, lane = tid & 63;
  const size_t base4 = (size_t)row * 256 + tid;
  ushort4 a4 = xin[base4];
  ushort4 c4 = y1b[base4];
  float v0 = b2f(a4.x) + b2f(c4.x), v1 = b2f(a4.y) + b2f(c4.y);
  float v2 = b2f(a4.z) + b2f(c4.z), v3 = b2f(a4.w) + b2f(c4.w);

  float s = v0 + v1 + v2 + v3;
#pragma unroll
  for (int off = 32; off; off >>= 1) s += __shfl_xor(s, off);
  __shared__ float red1[4], red2[4];
  if (lane == 0) red1[wave] = s;
  __syncthreads();
  float mean = (red1[0] + red1[1] + red1[2] + red1[3]) * (1.f / 1024.f);

  float d0 = v0 - mean, d1 = v1 - mean, d2 = v2 - mean, d3 = v3 - mean;
  float vs = d0 * d0 + d1 * d1 + d2 * d2 + d3 * d3;
#pragma unroll
  for (int off = 32; off; off >>= 1) vs += __shfl_xor(vs, off);
  if (lane == 0) red2[wave] = vs;
  __syncthreads();
  float var = (red2[0] + red2[1] + red2[2] + red2[3]) * (1.f / 1024.f);
  float rstd = rsqrtf(var + 1e-5f);

  const int col = tid * 4;
  float4 gg = *(const float4*)(g + col);
  float4 bb = *(const float4*)(bt + col);
  float o0 = d0 * rstd * gg.x + bb.x;
  float o1 = d1 * rstd * gg.y + bb.y;
  float o2 = d2 * rstd * gg.z + bb.z;
  float o3 = d3 * rstd * gg.w + bb.w;
  if (xout) {
    float4 oo; oo.x = o0; oo.y = o1; oo.z = o2; oo.w = o3;
    xout[base4] = oo;
  } else {
    ushort4 ob;
    ob.x = __builtin_bit_cast(unsigned short, (bf16)o0);
    ob.y = __builtin_bit_cast(unsigned short, (bf16)o1);
    ob.z = __builtin_bit_cast(unsigned short, (bf16)o2);
    ob.w = __builtin_bit_cast(unsigned short, (bf16)o3);
    xbf[base4] = ob;
  }
}

// ---------------------------------------------------------------- launch
extern "C" void kernel_launch(void* const* d_in, const int* in_sizes, int n_in,
                              void* d_out, int out_size, void* d_ws, size_t ws_size,
                              hipStream_t stream) {
  const float* qd  = (const float*)d_in[0];
  const float* qa  = (const float*)d_in[1];
  const float* Wk  = (const float*)d_in[2];
  const float* bk  = (const float*)d_in[3];
  const float* Wv  = (const float*)d_in[4];
  const float* bv  = (const float*)d_in[5];
  const float* Wo  = (const float*)d_in[6];
  const float* bo  = (const float*)d_in[7];
  const float* l1g = (const float*)d_in[8];
  const float* l1b = (const float*)d_in[9];
  const float* W1  = (const float*)d_in[10];
  const float* b1  = (const float*)d_in[11];
  const float* W2  = (const float*)d_in[12];
  const float* b2  = (const float*)d_in[13];
  const float* l2g = (const float*)d_in[14];
  const float* l2b = (const float*)d_in[15];

  const size_t DD = 1024 * 1024, DFD = 4096 * 1024, T = 8192;  // tokens
  bf16* wkb = (bf16*)d_ws;          // 3 contiguous D*D weights (wk, wv, wo)
  bf16* wvb = wkb + 2 * DD;
  bf16* wob = wvb + 2 * DD;
  bf16* w1b = wob + 2 * DD;         // 2 contiguous DF*D weights (w1, w2)
  bf16* w2b = w1b + 2 * DFD;
  bf16* regA = w2b + 2 * DFD;       // 33,554,432 bf16 elems region
  bf16* qbf = regA;                 // 8,388,608 each
  bf16* vbf = regA + 8388608;       // V^T layout: [bh][64][1024]
  bf16* abf = regA + 16777216;
  bf16* ff1 = regA;                 // reuse (q/v/attn dead during FFN)
  bf16* xbf = regA + 33554432;
  bf16* ybf = xbf + 8388608;
  bf16* g1b = ybf + 8388608;        // bf16 branch buffer (Wo / FF2 output)

  static bool gemm8_attr = false;
  if (!gemm8_attr) {
    (void)hipFuncSetAttribute(reinterpret_cast<const void*>(&gemm8<1, 1024>),
                              hipFuncAttributeMaxDynamicSharedMemorySize, 131072);
    gemm8_attr = true;
  }

  prep<<<dim3(1024, 1, 6), 256, 0, stream>>>(
      (const float4*)qd, (const float4*)qa, (ushort4*)xbf, (ushort4*)ybf,
      (const float4*)Wk, (const float4*)Wv, (const float4*)Wo,
      (const float4*)W1, (const float4*)W2,
      (ushort4*)wkb, (ushort4*)w1b, (int)(2 * DD / 4), (int)(2 * DFD / 4));

  for (int l = 0; l < 2; ++l) {
    // q/k projection (z=0, row-major) and v projection (z=1, per-head transposed)
    gemm_s<0, 1><<<dim3(8, 64, 2), 256, 0, stream>>>(
        xbf, wkb + l * DD, bk + l * 1024, qbf,
        ybf, wvb + l * DD, bv + l * 1024, vbf, 1024, 1024);
    attn_kernel<<<dim3(8, 128), 256, 0, stream>>>(qbf, vbf, abf);
    gemm_s<0, 0><<<dim3(8, 64), 256, 0, stream>>>(
        abf, wob + l * DD, bo + l * 1024, g1b, nullptr, nullptr, nullptr, nullptr, 1024, 1024);
    add_ln<<<T, 256, 0, stream>>>((const ushort4*)xbf, (const ushort4*)g1b,
                                  l1g + l * 1024, l1b + l * 1024,
                                  (ushort4*)xbf, nullptr);
    gemm8<1, 1024><<<dim3(16, 32), 512, 131072, stream>>>(
        xbf, w1b + l * DFD, b1 + l * 4096, ff1, 4096);
    gemm_s<0, 0><<<dim3(8, 64), 256, 0, stream>>>(
        ff1, w2b + l * DFD, b2 + l * 1024, g1b, nullptr, nullptr, nullptr, nullptr, 1024, 4096);
    const bool last = (l == 1);
    add_ln<<<T, 256, 0, stream>>>((const ushort4*)xbf, (const ushort4*)g1b,
                                  l2g + l * 1024, l2b + l * 1024,
                                  (ushort4*)xbf, last ? (float4*)d_out : nullptr);
  }
  (void)in_sizes; (void)n_in; (void)out_size; (void)ws_size;
}